// Round 1
// baseline (409.550 us; speedup 1.0000x reference)
//
#include <hip/hip_runtime.h>
#include <math.h>

#define Bb 4
#define Tt 512
#define Uu 128
#define Hh 512
#define Vv 41

// tanh via exp+rcp: tanh(x) = 1 - 2/(exp(2x)+1).  Handles saturation naturally
// (exp->0 => -1, exp->inf => 1).  ~5 VALU ops vs branchy libm tanhf.
__device__ __forceinline__ float fast_tanh(float x) {
    float e = __expf(2.0f * x);
    return 1.0f - 2.0f * __builtin_amdgcn_rcpf(e + 1.0f);
}

// -------- Kernel 1: target path: LN(gelu(tgt@W1+b1)@W2+b2) -> tgtP [B*U, H]
// One block per row (512 blocks, 256 threads, 2 columns/thread).
__global__ __launch_bounds__(256) void target_kernel(
    const float* __restrict__ tgt,
    const float* __restrict__ W1, const float* __restrict__ b1,
    const float* __restrict__ W2, const float* __restrict__ b2,
    const float* __restrict__ ln_g, const float* __restrict__ ln_b,
    float* __restrict__ tgtP)
{
    __shared__ float rows[Hh];
    __shared__ float h1s[Hh];
    __shared__ float red[16];

    const int r   = blockIdx.x;      // 0..B*U-1
    const int tid = threadIdx.x;     // 0..255
    const int j0 = tid, j1 = tid + 256;

    const float* trow = tgt + (size_t)r * Hh;
    rows[j0] = trow[j0];
    rows[j1] = trow[j1];
    __syncthreads();

    // GEMM1 + exact GELU
    float acc0 = b1[j0], acc1 = b1[j1];
    #pragma unroll 4
    for (int k = 0; k < Hh; ++k) {
        float rv = rows[k];
        acc0 = fmaf(rv, W1[k * Hh + j0], acc0);
        acc1 = fmaf(rv, W1[k * Hh + j1], acc1);
    }
    // exact GELU: 0.5*x*(1+erf(x/sqrt(2)))
    float g0 = 0.5f * acc0 * (1.0f + erff(acc0 * 0.70710678118654752f));
    float g1 = 0.5f * acc1 * (1.0f + erff(acc1 * 0.70710678118654752f));
    h1s[j0] = g0;
    h1s[j1] = g1;
    __syncthreads();

    // GEMM2
    float a0 = b2[j0], a1 = b2[j1];
    #pragma unroll 4
    for (int k = 0; k < Hh; ++k) {
        float rv = h1s[k];
        a0 = fmaf(rv, W2[k * Hh + j0], a0);
        a1 = fmaf(rv, W2[k * Hh + j1], a1);
    }

    // LayerNorm: mean/var over H (biased var, eps=1e-5)
    float s  = a0 + a1;
    float sq = a0 * a0 + a1 * a1;
    #pragma unroll
    for (int off = 32; off > 0; off >>= 1) {
        s  += __shfl_down(s,  off, 64);
        sq += __shfl_down(sq, off, 64);
    }
    const int wave = tid >> 6;
    if ((tid & 63) == 0) { red[wave] = s; red[8 + wave] = sq; }
    __syncthreads();
    if (tid == 0) {
        float ts = red[0] + red[1] + red[2] + red[3];
        float tq = red[8] + red[9] + red[10] + red[11];
        float mu = ts * (1.0f / Hh);
        float var = tq * (1.0f / Hh) - mu * mu;
        red[0] = mu;
        red[1] = rsqrtf(var + 1e-5f);
    }
    __syncthreads();
    const float mu = red[0], rstd = red[1];

    float* orow = tgtP + (size_t)r * Hh;
    orow[j0] = (a0 - mu) * rstd * ln_g[j0] + ln_b[j0];
    orow[j1] = (a1 - mu) * rstd * ln_g[j1] + ln_b[j1];
}

// -------- Kernel 2: joint: out[b,t,u,v] = sum_h tanh(src[b,t,h]+tgtP[b,u,h])*Wl[h,v] + bl[v]
// One block per (b,t); thread = u (128 threads); 41 fp32 accumulators/thread.
// Wl indices are wave-uniform -> compiler emits scalar loads (s_load) for weights.
__global__ __launch_bounds__(128) void joint_kernel(
    const float* __restrict__ src, const float* __restrict__ tgtP,
    const float* __restrict__ Wl, const float* __restrict__ bl,
    float* __restrict__ out)
{
    __shared__ float4 srow[Hh / 4];
    __shared__ float outTile[Uu * Vv];   // 5248 floats = 20.5 KB

    const int t = blockIdx.x;
    const int b = blockIdx.y;
    const int u = threadIdx.x;           // 0..127

    // stage src row (broadcast-read later)
    const float4* s4 = (const float4*)(src + ((size_t)(b * Tt + t)) * Hh);
    for (int i = u; i < Hh / 4; i += Uu) srow[i] = s4[i];
    __syncthreads();

    const float4* p4 = (const float4*)(tgtP + ((size_t)(b * Uu + u)) * Hh);

    float acc[Vv];
    #pragma unroll
    for (int v = 0; v < Vv; ++v) acc[v] = bl[v];

    for (int h4 = 0; h4 < Hh / 4; ++h4) {
        float4 pv = p4[h4];
        float4 sv = srow[h4];
        float a0 = fast_tanh(sv.x + pv.x);
        float a1 = fast_tanh(sv.y + pv.y);
        float a2 = fast_tanh(sv.z + pv.z);
        float a3 = fast_tanh(sv.w + pv.w);
        const float* w = Wl + (size_t)h4 * 4 * Vv;   // wave-uniform address
        #pragma unroll
        for (int v = 0; v < Vv; ++v) {
            float t0 = fmaf(a0, w[v], acc[v]);
            float t1 = fmaf(a1, w[Vv + v], t0);
            float t2 = fmaf(a2, w[2 * Vv + v], t1);
            acc[v]   = fmaf(a3, w[3 * Vv + v], t2);
        }
    }

    #pragma unroll
    for (int v = 0; v < Vv; ++v) outTile[u * Vv + v] = acc[v];
    __syncthreads();

    // coalesced write of the (t,b) tile: U*V contiguous floats
    float* obase = out + ((size_t)(b * Tt + t)) * Uu * Vv;
    for (int i = u; i < Uu * Vv; i += Uu) obase[i] = outTile[i];
}

// -------- Kernel 3: lengths passthrough (written as float per harness flat-f32 readback)
__global__ void len_kernel(const int* __restrict__ sl, const int* __restrict__ tl,
                           float* __restrict__ dst)
{
    const int i = threadIdx.x;
    if (i < Bb)            dst[i] = (float)sl[i];
    else if (i < 2 * Bb)   dst[i] = (float)tl[i - Bb];
}

extern "C" void kernel_launch(void* const* d_in, const int* in_sizes, int n_in,
                              void* d_out, int out_size, void* d_ws, size_t ws_size,
                              hipStream_t stream)
{
    const float* src  = (const float*)d_in[0];
    const int*   slen = (const int*)  d_in[1];
    const float* tgt  = (const float*)d_in[2];
    const int*   tlen = (const int*)  d_in[3];
    const float* W1   = (const float*)d_in[4];
    const float* b1   = (const float*)d_in[5];
    const float* W2   = (const float*)d_in[6];
    const float* b2   = (const float*)d_in[7];
    const float* ln_g = (const float*)d_in[8];
    const float* ln_b = (const float*)d_in[9];
    const float* Wl   = (const float*)d_in[10];
    const float* bl   = (const float*)d_in[11];

    float* out  = (float*)d_out;
    float* tgtP = (float*)d_ws;          // B*U*H fp32 = 1 MB scratch

    hipLaunchKernelGGL(target_kernel, dim3(Bb * Uu), dim3(256), 0, stream,
                       tgt, W1, b1, W2, b2, ln_g, ln_b, tgtP);
    hipLaunchKernelGGL(joint_kernel, dim3(Tt, Bb), dim3(128), 0, stream,
                       src, tgtP, Wl, bl, out);
    hipLaunchKernelGGL(len_kernel, dim3(1), dim3(64), 0, stream,
                       slen, tlen, out + (size_t)Bb * Tt * Uu * Vv);
}

// Round 2
// 232.919 us; speedup vs baseline: 1.7583x; 1.7583x over previous
//
#include <hip/hip_runtime.h>
#include <math.h>

#define Bb 4
#define Tt 512
#define Uu 128
#define Hh 512
#define Vv 41

typedef __attribute__((ext_vector_type(8))) short short8;
typedef __attribute__((ext_vector_type(4))) float f32x4;

// tanh(x) = 1 - 2/(exp(2x)+1); saturates correctly at +-1.
__device__ __forceinline__ float fast_tanh(float x) {
    float e = __expf(2.0f * x);
    return 1.0f - 2.0f * __builtin_amdgcn_rcpf(e + 1.0f);
}

// round-to-nearest bf16 (ties up) of two floats, packed [lo | hi] in one u32
__device__ __forceinline__ unsigned pack_bf16(float hi, float lo) {
    unsigned xh = __float_as_uint(hi) + 0x8000u;
    unsigned xl = __float_as_uint(lo) + 0x8000u;
    // combined {S0=xh : S1=xl}; take bytes 2,3 of xl then 2,3 of xh
    return __builtin_amdgcn_perm(xh, xl, 0x07060302);
}

// -------- Prep: Wl [H,V] fp32 -> Wt [48,512] bf16 (transposed, n-padded w/ 0)
__global__ void prep_wt(const float* __restrict__ Wl, unsigned short* __restrict__ Wt) {
    int idx = blockIdx.x * 256 + threadIdx.x;      // 0..24575
    int n = idx >> 9, k = idx & 511;
    float v = (n < Vv) ? Wl[k * Vv + n] : 0.0f;
    unsigned x = __float_as_uint(v);
    x += 0x7fffu + ((x >> 16) & 1u);               // RNE
    Wt[(n << 9) | k] = (unsigned short)(x >> 16);
}

// -------- Target path: LN(gelu(tgt@W1+b1)@W2+b2) -> tgtP [B*U, H]
// 2 rows/block -> 256 blocks (1/CU), 256 threads, 2 cols/thread.
__global__ __launch_bounds__(256) void target_kernel(
    const float* __restrict__ tgt,
    const float* __restrict__ W1, const float* __restrict__ b1,
    const float* __restrict__ W2, const float* __restrict__ b2,
    const float* __restrict__ ln_g, const float* __restrict__ ln_b,
    float* __restrict__ tgtP)
{
    __shared__ float rows[2 * Hh];
    __shared__ float h1s[2 * Hh];
    __shared__ float redS[2][4], redQ[2][4], stats[2][2];

    const int tid = threadIdx.x;
    const int r0 = blockIdx.x * 2;
    const int j0 = tid, j1 = tid + 256;

    const float4* t4 = (const float4*)(tgt + (size_t)r0 * Hh);
    ((float4*)rows)[tid] = t4[tid];                // 2*512 floats = 256 float4
    __syncthreads();

    float a0[2], a1[2];
    a0[0] = b1[j0]; a0[1] = a0[0]; a1[0] = b1[j1]; a1[1] = a1[0];

    const float4* rows4 = (const float4*)rows;
    #pragma unroll 2
    for (int k4 = 0; k4 < 128; ++k4) {
        float4 rv0 = rows4[k4];
        float4 rv1 = rows4[128 + k4];
        const float* w = W1 + (size_t)k4 * 4 * Hh;
        #pragma unroll
        for (int i = 0; i < 4; ++i) {
            float w0 = w[i * Hh + j0], w1 = w[i * Hh + j1];
            float e0 = (&rv0.x)[i], e1 = (&rv1.x)[i];
            a0[0] = fmaf(e0, w0, a0[0]); a1[0] = fmaf(e0, w1, a1[0]);
            a0[1] = fmaf(e1, w0, a0[1]); a1[1] = fmaf(e1, w1, a1[1]);
        }
    }
    #pragma unroll
    for (int r = 0; r < 2; ++r) {
        float g0 = 0.5f * a0[r] * (1.0f + erff(a0[r] * 0.70710678118654752f));
        float g1 = 0.5f * a1[r] * (1.0f + erff(a1[r] * 0.70710678118654752f));
        h1s[r * Hh + j0] = g0;
        h1s[r * Hh + j1] = g1;
    }
    __syncthreads();

    a0[0] = b2[j0]; a0[1] = a0[0]; a1[0] = b2[j1]; a1[1] = a1[0];
    const float4* h4 = (const float4*)h1s;
    #pragma unroll 2
    for (int k4 = 0; k4 < 128; ++k4) {
        float4 rv0 = h4[k4];
        float4 rv1 = h4[128 + k4];
        const float* w = W2 + (size_t)k4 * 4 * Hh;
        #pragma unroll
        for (int i = 0; i < 4; ++i) {
            float w0 = w[i * Hh + j0], w1 = w[i * Hh + j1];
            float e0 = (&rv0.x)[i], e1 = (&rv1.x)[i];
            a0[0] = fmaf(e0, w0, a0[0]); a1[0] = fmaf(e0, w1, a1[0]);
            a0[1] = fmaf(e1, w0, a0[1]); a1[1] = fmaf(e1, w1, a1[1]);
        }
    }

    const int lane = tid & 63, wave = tid >> 6;
    #pragma unroll
    for (int r = 0; r < 2; ++r) {
        float s = a0[r] + a1[r];
        float q = a0[r] * a0[r] + a1[r] * a1[r];
        #pragma unroll
        for (int off = 32; off > 0; off >>= 1) {
            s += __shfl_down(s, off, 64);
            q += __shfl_down(q, off, 64);
        }
        if (lane == 0) { redS[r][wave] = s; redQ[r][wave] = q; }
    }
    __syncthreads();
    if (tid < 2) {
        int r = tid;
        float ts = redS[r][0] + redS[r][1] + redS[r][2] + redS[r][3];
        float tq = redQ[r][0] + redQ[r][1] + redQ[r][2] + redQ[r][3];
        float mu = ts * (1.0f / Hh);
        float var = tq * (1.0f / Hh) - mu * mu;
        stats[r][0] = mu;
        stats[r][1] = rsqrtf(var + 1e-5f);
    }
    __syncthreads();
    #pragma unroll
    for (int r = 0; r < 2; ++r) {
        float mu = stats[r][0], rs = stats[r][1];
        float* orow = tgtP + (size_t)(r0 + r) * Hh;
        orow[j0] = (a0[r] - mu) * rs * ln_g[j0] + ln_b[j0];
        orow[j1] = (a1[r] - mu) * rs * ln_g[j1] + ln_b[j1];
    }
}

// -------- Joint: out[b,t,u,v] = tanh(src[b,t,:]+tgtP[b,u,:]) @ Wl + bl
// One block per (b,t), 256 threads (4 waves).  Activation tile A[128u][128k]
// bf16 in LDS (row stride 272B = 256B data + 16B pad), MFMA 16x16x32 bf16.
// B-fragments read directly from transposed Wt in global (L2-hot, k-contig).
__global__ __launch_bounds__(256) void joint_mfma(
    const float* __restrict__ src, const float* __restrict__ tgtP,
    const unsigned short* __restrict__ Wt, const float* __restrict__ bl,
    float* __restrict__ out)
{
    __shared__ __align__(16) char smem[2048 + 128 * 272];   // src row + A tile
    float* srcl = (float*)smem;
    char* Ab = smem + 2048;

    const int t = blockIdx.x, b = blockIdx.y;
    const int tid = threadIdx.x;
    const int lane = tid & 63, wave = tid >> 6;
    const int ncol = lane & 15, quad = lane >> 4;

    // stage src row (512 fp32)
    const float4* s4 = (const float4*)(src + ((size_t)(b * Tt + t)) * Hh);
    if (tid < 128) ((float4*)srcl)[tid] = s4[tid];

    // bias fragment per n-tile
    float bln[3];
    #pragma unroll
    for (int nt = 0; nt < 3; ++nt) {
        int n = nt * 16 + ncol;
        bln[nt] = (n < Vv) ? bl[n] : 0.0f;
    }

    f32x4 acc[2][3];
    #pragma unroll
    for (int mi = 0; mi < 2; ++mi)
        #pragma unroll
        for (int nt = 0; nt < 3; ++nt)
            acc[mi][nt] = (f32x4){0.f, 0.f, 0.f, 0.f};

    __syncthreads();

    const float4* p4 = (const float4*)(tgtP + ((size_t)b * Uu) * Hh);
    const int mt0 = wave * 2;

    for (int chunk = 0; chunk < 4; ++chunk) {
        // ---- activation formation: A[u][k0..k0+128) bf16
        #pragma unroll
        for (int it = 0; it < 16; ++it) {
            int idx = it * 256 + tid;
            int u = idx >> 5, k4 = idx & 31;      // 32 float4 per 128-k chunk
            float4 pv = p4[u * 128 + chunk * 32 + k4];
            float4 sv = ((const float4*)srcl)[chunk * 32 + k4];
            float x0 = fast_tanh(sv.x + pv.x);
            float x1 = fast_tanh(sv.y + pv.y);
            float x2 = fast_tanh(sv.z + pv.z);
            float x3 = fast_tanh(sv.w + pv.w);
            uint2 pk;
            pk.x = pack_bf16(x1, x0);
            pk.y = pack_bf16(x3, x2);
            *(uint2*)(Ab + u * 272 + k4 * 8) = pk;
        }
        __syncthreads();

        // ---- MFMA over this k-chunk (4 ksteps of 32)
        #pragma unroll
        for (int ks = 0; ks < 4; ++ks) {
            int kk = ks * 32 + quad * 8;          // chunk-local k for this lane
            short8 af0 = *(const short8*)(Ab + (mt0 * 16 + ncol) * 272 + kk * 2);
            short8 af1 = *(const short8*)(Ab + ((mt0 + 1) * 16 + ncol) * 272 + kk * 2);
            #pragma unroll
            for (int nt = 0; nt < 3; ++nt) {
                short8 bf = *(const short8*)(Wt + ((size_t)(nt * 16 + ncol)) * Hh
                                                 + chunk * 128 + kk);
                acc[0][nt] = __builtin_amdgcn_mfma_f32_16x16x32_bf16(af0, bf, acc[0][nt], 0, 0, 0);
                acc[1][nt] = __builtin_amdgcn_mfma_f32_16x16x32_bf16(af1, bf, acc[1][nt], 0, 0, 0);
            }
        }
        __syncthreads();
    }

    // ---- epilogue: C layout col=lane&15, row=quad*4+reg
    float* ob = out + ((size_t)(b * Tt + t)) * Uu * Vv;
    #pragma unroll
    for (int mi = 0; mi < 2; ++mi) {
        #pragma unroll
        for (int nt = 0; nt < 3; ++nt) {
            int n = nt * 16 + ncol;
            if (n < Vv) {
                #pragma unroll
                for (int r = 0; r < 4; ++r) {
                    int m = (mt0 + mi) * 16 + quad * 4 + r;
                    ob[m * Vv + n] = acc[mi][nt][r] + bln[nt];
                }
            }
        }
    }
}

// -------- lengths passthrough (harness reads whole out buffer as f32)
__global__ void len_kernel(const int* __restrict__ sl, const int* __restrict__ tl,
                           float* __restrict__ dst)
{
    const int i = threadIdx.x;
    if (i < Bb)            dst[i] = (float)sl[i];
    else if (i < 2 * Bb)   dst[i] = (float)tl[i - Bb];
}

extern "C" void kernel_launch(void* const* d_in, const int* in_sizes, int n_in,
                              void* d_out, int out_size, void* d_ws, size_t ws_size,
                              hipStream_t stream)
{
    const float* src  = (const float*)d_in[0];
    const int*   slen = (const int*)  d_in[1];
    const float* tgt  = (const float*)d_in[2];
    const int*   tlen = (const int*)  d_in[3];
    const float* W1   = (const float*)d_in[4];
    const float* b1   = (const float*)d_in[5];
    const float* W2   = (const float*)d_in[6];
    const float* b2   = (const float*)d_in[7];
    const float* ln_g = (const float*)d_in[8];
    const float* ln_b = (const float*)d_in[9];
    const float* Wl   = (const float*)d_in[10];
    const float* bl   = (const float*)d_in[11];

    float* out  = (float*)d_out;
    float* tgtP = (float*)d_ws;                                  // 1 MB
    unsigned short* Wt = (unsigned short*)((char*)d_ws + (size_t)Bb * Uu * Hh * 4);  // 48 KB

    hipLaunchKernelGGL(prep_wt, dim3(96), dim3(256), 0, stream, Wl, Wt);
    hipLaunchKernelGGL(target_kernel, dim3(Bb * Uu / 2), dim3(256), 0, stream,
                       tgt, W1, b1, W2, b2, ln_g, ln_b, tgtP);
    hipLaunchKernelGGL(joint_mfma, dim3(Tt, Bb), dim3(256), 0, stream,
                       src, tgtP, Wt, bl, out);
    hipLaunchKernelGGL(len_kernel, dim3(1), dim3(64), 0, stream,
                       slen, tlen, out + (size_t)Bb * Tt * Uu * Vv);
}

// Round 3
// 231.454 us; speedup vs baseline: 1.7695x; 1.0063x over previous
//
#include <hip/hip_runtime.h>
#include <math.h>

#define Bb 4
#define Tt 512
#define Uu 128
#define Hh 512
#define Vv 41

typedef __attribute__((ext_vector_type(8))) short short8;
typedef __attribute__((ext_vector_type(4))) float f32x4;

// Pade[3,2] tanh + clamp: max abs err ~0.016 (at |x|~2.3), exact enough for
// 2%-of-absmax(=9.84) tolerance.  1 transcendental (rcp) vs 2 for exp-form.
__device__ __forceinline__ float ptanh(float x) {
    float t = x * x;
    float num = x * (15.0f + t);
    float den = fmaf(t, 6.0f, 15.0f);
    float r = num * __builtin_amdgcn_rcpf(den);
    return fmaxf(-1.0f, fminf(1.0f, r));
}

// pack two floats to bf16 (round-up-at-tie), [lo | hi] in one u32
__device__ __forceinline__ unsigned pack_bf16(float hi, float lo) {
    unsigned xh = __float_as_uint(hi) + 0x8000u;
    unsigned xl = __float_as_uint(lo) + 0x8000u;
    return __builtin_amdgcn_perm(xh, xl, 0x07060302);
}

__device__ __forceinline__ unsigned short bf16_rne(float v) {
    unsigned x = __float_as_uint(v);
    x += 0x7fffu + ((x >> 16) & 1u);
    return (unsigned short)(x >> 16);
}

// -------- Prep: W1,W2 [512,512] and Wl [512,41] fp32 -> bf16 transposed [n][k]
__global__ __launch_bounds__(256) void prep_weights(
    const float* __restrict__ W1, const float* __restrict__ W2,
    const float* __restrict__ Wl,
    unsigned short* __restrict__ Wt1, unsigned short* __restrict__ Wt2,
    unsigned short* __restrict__ Wtl)
{
    int idx = blockIdx.x * 256 + threadIdx.x;        // 0 .. 548863
    if (idx < 2 * 512 * 512) {
        const float* W = (idx < 512 * 512) ? W1 : W2;
        unsigned short* O = (idx < 512 * 512) ? Wt1 : Wt2;
        int i = idx & (512 * 512 - 1);
        int n = i >> 9, k = i & 511;
        O[(n << 9) | k] = bf16_rne(W[k * 512 + n]);
    } else {
        int i = idx - 2 * 512 * 512;                  // 0 .. 48*512-1
        int n = i >> 9, k = i & 511;
        float v = (n < Vv) ? Wl[k * Vv + n] : 0.0f;
        Wtl[(n << 9) | k] = bf16_rne(v);
    }
}

// -------- Target path, fused MFMA: LN(gelu(tgt@W1+b1)@W2+b2) -> tgtP [B*U,512]
// 32 blocks x 16 rows, 512 threads (8 waves), each wave owns 64 n-columns.
__global__ __launch_bounds__(512) void target_kernel(
    const float* __restrict__ tgt,
    const unsigned short* __restrict__ Wt1, const float* __restrict__ b1,
    const unsigned short* __restrict__ Wt2, const float* __restrict__ b2,
    const float* __restrict__ ln_g, const float* __restrict__ ln_b,
    float* __restrict__ tgtP)
{
    __shared__ unsigned short At[16][520];   // A tile, then h1 tile (stride 1040B = 4 mod 32 dwords: conflict-free)
    __shared__ float Ct[16][516];            // GEMM2 output for LN
    __shared__ float stats[16][2];

    const int tid = threadIdx.x;
    const int lane = tid & 63, wave = tid >> 6;
    const int ncol = lane & 15, quad = lane >> 4;
    const int r0 = blockIdx.x * 16;
    const int n0 = wave * 64;

    // stage A: 16 rows x 512 fp32 -> bf16 LDS
    {
        const float4* t4 = (const float4*)(tgt + (size_t)r0 * Hh);
        #pragma unroll
        for (int j = 0; j < 4; ++j) {
            int fi = tid + j * 512;          // 0..2047 float4s
            int row = fi >> 7, c4 = fi & 127;
            float4 v = t4[fi];
            uint2 pk;
            pk.x = pack_bf16(v.y, v.x);
            pk.y = pack_bf16(v.w, v.z);
            *(uint2*)&At[row][c4 * 4] = pk;
        }
    }
    __syncthreads();

    f32x4 acc[4];
    #pragma unroll
    for (int i = 0; i < 4; ++i) acc[i] = (f32x4){0.f, 0.f, 0.f, 0.f};

    // GEMM1: A-frags from LDS, B-frags from global bf16 (L2-hot)
    #pragma unroll 2
    for (int ks = 0; ks < 16; ++ks) {
        int kb = ks * 32 + quad * 8;
        short8 af = *(const short8*)&At[ncol][kb];
        #pragma unroll
        for (int nt = 0; nt < 4; ++nt) {
            short8 bfr = *(const short8*)(Wt1 + (size_t)(n0 + nt * 16 + ncol) * Hh + kb);
            acc[nt] = __builtin_amdgcn_mfma_f32_16x16x32_bf16(af, bfr, acc[nt], 0, 0, 0);
        }
    }
    __syncthreads();   // all waves done reading At

    // GELU(+b1) -> h1 (reuse At)
    #pragma unroll
    for (int nt = 0; nt < 4; ++nt) {
        int n = n0 + nt * 16 + ncol;
        float bias = b1[n];
        #pragma unroll
        for (int r = 0; r < 4; ++r) {
            float v = acc[nt][r] + bias;
            float g = 0.5f * v * (1.0f + erff(v * 0.70710678118654752f));
            At[quad * 4 + r][n] = bf16_rne(g);
        }
        acc[nt] = (f32x4){0.f, 0.f, 0.f, 0.f};
    }
    __syncthreads();

    // GEMM2
    #pragma unroll 2
    for (int ks = 0; ks < 16; ++ks) {
        int kb = ks * 32 + quad * 8;
        short8 af = *(const short8*)&At[ncol][kb];
        #pragma unroll
        for (int nt = 0; nt < 4; ++nt) {
            short8 bfr = *(const short8*)(Wt2 + (size_t)(n0 + nt * 16 + ncol) * Hh + kb);
            acc[nt] = __builtin_amdgcn_mfma_f32_16x16x32_bf16(af, bfr, acc[nt], 0, 0, 0);
        }
    }

    // +b2 -> Ct for LN
    #pragma unroll
    for (int nt = 0; nt < 4; ++nt) {
        int n = n0 + nt * 16 + ncol;
        float bias = b2[n];
        #pragma unroll
        for (int r = 0; r < 4; ++r)
            Ct[quad * 4 + r][n] = acc[nt][r] + bias;
    }
    __syncthreads();

    // LayerNorm: 32 threads per row
    const int row = tid >> 5, l32 = tid & 31;
    const float4* cr = (const float4*)&Ct[row][0];
    float s = 0.f, q = 0.f;
    #pragma unroll
    for (int j = 0; j < 4; ++j) {
        float4 v = cr[l32 + 32 * j];
        s += v.x + v.y + v.z + v.w;
        q += v.x * v.x + v.y * v.y + v.z * v.z + v.w * v.w;
    }
    #pragma unroll
    for (int off = 16; off > 0; off >>= 1) {
        s += __shfl_down(s, off, 32);
        q += __shfl_down(q, off, 32);
    }
    if (l32 == 0) {
        float mu = s * (1.0f / Hh);
        float var = q * (1.0f / Hh) - mu * mu;
        stats[row][0] = mu;
        stats[row][1] = rsqrtf(var + 1e-5f);
    }
    __syncthreads();
    {
        float mu = stats[row][0], rs = stats[row][1];
        float* orow = tgtP + (size_t)(r0 + row) * Hh;
        #pragma unroll
        for (int j = 0; j < 4; ++j) {
            int c4 = l32 + 32 * j;
            float4 v = cr[c4];
            float4 g4 = ((const float4*)ln_g)[c4];
            float4 b4 = ((const float4*)ln_b)[c4];
            float4 o;
            o.x = (v.x - mu) * rs * g4.x + b4.x;
            o.y = (v.y - mu) * rs * g4.y + b4.y;
            o.z = (v.z - mu) * rs * g4.z + b4.z;
            o.w = (v.w - mu) * rs * g4.w + b4.w;
            ((float4*)orow)[c4] = o;
        }
    }
}

// -------- Joint: out[b,t,u,v] = tanh(src[b,t,:]+tgtP[b,u,:]) @ Wl + bl
// Register-direct A-fragments: each lane computes tanh for its own MFMA
// fragment rows (u = wave*32+ncol, +16).  No A-tile LDS, no per-chunk
// barriers.  B-frags from transposed bf16 Wtl in global (L1/L2-hot).
__global__ __launch_bounds__(256) void joint_mfma(
    const float* __restrict__ src, const float* __restrict__ tgtP,
    const unsigned short* __restrict__ Wtl, const float* __restrict__ bl,
    float* __restrict__ out)
{
    __shared__ float srcl[Hh];

    const int t = blockIdx.x, b = blockIdx.y;
    const int tid = threadIdx.x;
    const int lane = tid & 63, wave = tid >> 6;
    const int ncol = lane & 15, quad = lane >> 4;

    const float4* s4 = (const float4*)(src + ((size_t)(b * Tt + t)) * Hh);
    if (tid < 128) ((float4*)srcl)[tid] = s4[tid];

    float bln[3];
    #pragma unroll
    for (int nt = 0; nt < 3; ++nt) {
        int n = nt * 16 + ncol;
        bln[nt] = (n < Vv) ? bl[n] : 0.0f;
    }

    f32x4 acc[2][3];
    #pragma unroll
    for (int mi = 0; mi < 2; ++mi)
        #pragma unroll
        for (int nt = 0; nt < 3; ++nt)
            acc[mi][nt] = (f32x4){0.f, 0.f, 0.f, 0.f};

    __syncthreads();

    const int u0 = wave * 32 + ncol;                      // af0 row; af1 = +16
    const float* p0 = tgtP + ((size_t)(b * Uu) + u0) * Hh;
    const float* p1 = p0 + 16 * Hh;

    #pragma unroll 2
    for (int ks = 0; ks < 16; ++ks) {
        const int kb = ks * 32 + quad * 8;
        float4 sA = ((const float4*)srcl)[kb >> 2];       // broadcast within quad
        float4 sB = ((const float4*)srcl)[(kb >> 2) + 1];
        float4 a0 = *(const float4*)(p0 + kb);
        float4 a1 = *(const float4*)(p0 + kb + 4);
        float4 c0 = *(const float4*)(p1 + kb);
        float4 c1 = *(const float4*)(p1 + kb + 4);

        union { uint4 u; short8 s; } f0, f1;
        f0.u.x = pack_bf16(ptanh(sA.y + a0.y), ptanh(sA.x + a0.x));
        f0.u.y = pack_bf16(ptanh(sA.w + a0.w), ptanh(sA.z + a0.z));
        f0.u.z = pack_bf16(ptanh(sB.y + a1.y), ptanh(sB.x + a1.x));
        f0.u.w = pack_bf16(ptanh(sB.w + a1.w), ptanh(sB.z + a1.z));
        f1.u.x = pack_bf16(ptanh(sA.y + c0.y), ptanh(sA.x + c0.x));
        f1.u.y = pack_bf16(ptanh(sA.w + c0.w), ptanh(sA.z + c0.z));
        f1.u.z = pack_bf16(ptanh(sB.y + c1.y), ptanh(sB.x + c1.x));
        f1.u.w = pack_bf16(ptanh(sB.w + c1.w), ptanh(sB.z + c1.z));

        #pragma unroll
        for (int nt = 0; nt < 3; ++nt) {
            short8 bfr = *(const short8*)(Wtl + (size_t)(nt * 16 + ncol) * Hh + kb);
            acc[0][nt] = __builtin_amdgcn_mfma_f32_16x16x32_bf16(f0.s, bfr, acc[0][nt], 0, 0, 0);
            acc[1][nt] = __builtin_amdgcn_mfma_f32_16x16x32_bf16(f1.s, bfr, acc[1][nt], 0, 0, 0);
        }
    }

    // epilogue: C layout col=lane&15, row=quad*4+reg  (validated round 2)
    float* ob = out + ((size_t)(b * Tt + t)) * Uu * Vv;
    const int mt0 = wave * 2;
    #pragma unroll
    for (int mi = 0; mi < 2; ++mi) {
        #pragma unroll
        for (int nt = 0; nt < 3; ++nt) {
            int n = nt * 16 + ncol;
            if (n < Vv) {
                #pragma unroll
                for (int r = 0; r < 4; ++r) {
                    int m = (mt0 + mi) * 16 + quad * 4 + r;
                    ob[m * Vv + n] = acc[mi][nt][r] + bln[nt];
                }
            }
        }
    }
}

// -------- lengths passthrough (harness reads whole out buffer as f32)
__global__ void len_kernel(const int* __restrict__ sl, const int* __restrict__ tl,
                           float* __restrict__ dst)
{
    const int i = threadIdx.x;
    if (i < Bb)            dst[i] = (float)sl[i];
    else if (i < 2 * Bb)   dst[i] = (float)tl[i - Bb];
}

extern "C" void kernel_launch(void* const* d_in, const int* in_sizes, int n_in,
                              void* d_out, int out_size, void* d_ws, size_t ws_size,
                              hipStream_t stream)
{
    const float* src  = (const float*)d_in[0];
    const int*   slen = (const int*)  d_in[1];
    const float* tgt  = (const float*)d_in[2];
    const int*   tlen = (const int*)  d_in[3];
    const float* W1   = (const float*)d_in[4];
    const float* b1   = (const float*)d_in[5];
    const float* W2   = (const float*)d_in[6];
    const float* b2   = (const float*)d_in[7];
    const float* ln_g = (const float*)d_in[8];
    const float* ln_b = (const float*)d_in[9];
    const float* Wl   = (const float*)d_in[10];
    const float* bl   = (const float*)d_in[11];

    float* out  = (float*)d_out;
    // ws layout: tgtP fp32 1MB | Wt1 bf16 512KB | Wt2 bf16 512KB | Wtl bf16 48KB
    float* tgtP = (float*)d_ws;
    unsigned short* Wt1 = (unsigned short*)((char*)d_ws + 1048576);
    unsigned short* Wt2 = (unsigned short*)((char*)d_ws + 1048576 + 524288);
    unsigned short* Wtl = (unsigned short*)((char*)d_ws + 1048576 + 1048576);

    hipLaunchKernelGGL(prep_weights, dim3(2144), dim3(256), 0, stream,
                       W1, W2, Wl, Wt1, Wt2, Wtl);
    hipLaunchKernelGGL(target_kernel, dim3(Bb * Uu / 16), dim3(512), 0, stream,
                       tgt, Wt1, b1, Wt2, b2, ln_g, ln_b, tgtP);
    hipLaunchKernelGGL(joint_mfma, dim3(Tt, Bb), dim3(256), 0, stream,
                       src, tgtP, Wtl, bl, out);
    hipLaunchKernelGGL(len_kernel, dim3(1), dim3(64), 0, stream,
                       slen, tlen, out + (size_t)Bb * Tt * Uu * Vv);
}

// Round 4
// 150.117 us; speedup vs baseline: 2.7282x; 1.5418x over previous
//
#include <hip/hip_runtime.h>
#include <math.h>

#define Bb 4
#define Tt 512
#define Uu 128
#define Hh 512
#define Vv 41

typedef __attribute__((ext_vector_type(8))) short short8;
typedef __attribute__((ext_vector_type(4))) float f32x4;
typedef __attribute__((ext_vector_type(2))) float v2f;

// RNE bf16 pack of two floats -> u32 [lo | hi<<16]
__device__ __forceinline__ unsigned pack_bf16_rne(float hi, float lo) {
    unsigned xh = __float_as_uint(hi); xh += 0x7fffu + ((xh >> 16) & 1u);
    unsigned xl = __float_as_uint(lo); xl += 0x7fffu + ((xl >> 16) & 1u);
    return __builtin_amdgcn_perm(xh, xl, 0x07060302);
}

// tanh approx: clamp x to [-3,3], odd minimax cubic in t=x^2 (max err ~0.024),
// truncating bf16 pack of the pair.  No transcendentals.
__device__ __forceinline__ unsigned tanh2_pack(v2f x) {
    v2f xc;
    xc.x = fminf(3.0f, fmaxf(-3.0f, x.x));
    xc.y = fminf(3.0f, fmaxf(-3.0f, x.y));
    v2f t = xc * xc;
    v2f p = t * (-0.00140725f) + 0.0288922f;
    p = p * t + (-0.2177528f);
    p = p * t + 0.9707868f;
    v2f g = xc * p;
    return __builtin_amdgcn_perm(__float_as_uint(g.y), __float_as_uint(g.x), 0x07060302);
}

// -------- Prep: pack W1,W2 (512x512) and Wl (512x41, n-padded to 48) into
// MFMA B-fragment order: Wp[ntile][kstep][lane][8 bf16], so a wave's B-frag
// load is one contiguous 1KB.  LDS-transposed 64x64 tiles, coalesced R/W.
__global__ __launch_bounds__(256) void prep_pack(
    const float* __restrict__ W1, const float* __restrict__ W2,
    const float* __restrict__ Wl,
    unsigned short* __restrict__ Wp1, unsigned short* __restrict__ Wp2,
    unsigned short* __restrict__ Wpl)
{
    __shared__ float T[64][65];
    const int bid = blockIdx.x, tid = threadIdx.x;
    const float* Wsrc; unsigned short* Wdst; int k0, n0, isWl;
    if (bid < 64)       { Wsrc = W1; Wdst = Wp1; k0 = (bid >> 3) * 64; n0 = (bid & 7) * 64; isWl = 0; }
    else if (bid < 128) { Wsrc = W2; Wdst = Wp2; k0 = ((bid - 64) >> 3) * 64; n0 = ((bid - 64) & 7) * 64; isWl = 0; }
    else                { Wsrc = Wl; Wdst = Wpl; k0 = (bid - 128) * 64; n0 = 0; isWl = 1; }

    #pragma unroll
    for (int i = 0; i < 16; ++i) {
        int idx = i * 256 + tid;                 // 0..4095
        int kk = idx >> 6, nn = idx & 63;
        float v;
        if (isWl) v = (nn < Vv) ? Wl[(k0 + kk) * Vv + nn] : 0.0f;
        else      v = Wsrc[(size_t)(k0 + kk) * 512 + n0 + nn];
        T[kk][nn] = v;
    }
    __syncthreads();

    #pragma unroll
    for (int i = 0; i < 2; ++i) {
        int task = i * 256 + tid;                // 0..511
        int nn = task & 63, kg = task >> 6;
        if (isWl && nn >= 48) continue;
        int n = n0 + nn, k = k0 + kg * 8;
        float e[8];
        #pragma unroll
        for (int j = 0; j < 8; ++j) e[j] = T[kg * 8 + j][nn];
        uint4 pk;
        pk.x = pack_bf16_rne(e[1], e[0]);
        pk.y = pack_bf16_rne(e[3], e[2]);
        pk.z = pack_bf16_rne(e[5], e[4]);
        pk.w = pack_bf16_rne(e[7], e[6]);
        int ntg = n >> 4, ncol = n & 15;
        int ks = (k >> 5) & 15, quad = (k >> 3) & 3;
        int lane = quad * 16 + ncol;
        *(uint4*)(Wdst + (size_t)((ntg * 16 + ks) * 64 + lane) * 8) = pk;
    }
}

// -------- Target path, fused MFMA: LN(gelu(tgt@W1+b1)@W2+b2) -> tgtPf
// tgtPf layout: [b][k/8][u][8 floats]  (joint A-operand fragment order).
// 32 blocks x 16 rows, 512 threads (8 waves), wave owns 64 n-columns.
__global__ __launch_bounds__(512) void target_kernel(
    const float* __restrict__ tgt,
    const unsigned short* __restrict__ Wp1, const float* __restrict__ b1,
    const unsigned short* __restrict__ Wp2, const float* __restrict__ b2,
    const float* __restrict__ ln_g, const float* __restrict__ ln_b,
    float* __restrict__ tgtPf)
{
    __shared__ unsigned short At[16][520];   // stride 1040B == 4 mod 32 dwords: 2-way max (free)
    __shared__ float Ct[16][516];
    __shared__ float stats[16][2];

    const int tid = threadIdx.x;
    const int lane = tid & 63, wave = tid >> 6;
    const int ncol = lane & 15, quad = lane >> 4;
    const int r0 = blockIdx.x * 16;

    {   // stage A: 16 rows x 512 fp32 -> bf16 LDS
        const float4* t4 = (const float4*)(tgt + (size_t)r0 * Hh);
        #pragma unroll
        for (int j = 0; j < 4; ++j) {
            int fi = tid + j * 512;
            int row = fi >> 7, c4 = fi & 127;
            float4 v = t4[fi];
            uint2 pk;
            pk.x = pack_bf16_rne(v.y, v.x);
            pk.y = pack_bf16_rne(v.w, v.z);
            *(uint2*)&At[row][c4 * 4] = pk;
        }
    }
    __syncthreads();

    f32x4 acc[4];
    #pragma unroll
    for (int i = 0; i < 4; ++i) acc[i] = (f32x4){0.f, 0.f, 0.f, 0.f};

    const unsigned short* bp1 = Wp1 + (size_t)(wave * 4) * 8192 + lane * 8;
    const unsigned short* bp2 = Wp2 + (size_t)(wave * 4) * 8192 + lane * 8;

    // GEMM1: A-frags from LDS, B-frags packed-coalesced from global
    #pragma unroll 2
    for (int ks = 0; ks < 16; ++ks) {
        int kb = ks * 32 + quad * 8;
        short8 af = *(const short8*)&At[ncol][kb];
        #pragma unroll
        for (int nt = 0; nt < 4; ++nt) {
            short8 bfr = *(const short8*)(bp1 + nt * 8192 + ks * 512);
            acc[nt] = __builtin_amdgcn_mfma_f32_16x16x32_bf16(af, bfr, acc[nt], 0, 0, 0);
        }
    }
    __syncthreads();

    // GELU(+b1) -> h1 (reuse At)
    #pragma unroll
    for (int nt = 0; nt < 4; ++nt) {
        int n = wave * 64 + nt * 16 + ncol;
        float bias = b1[n];
        #pragma unroll
        for (int r = 0; r < 4; ++r) {
            float v = acc[nt][r] + bias;
            float g = 0.5f * v * (1.0f + erff(v * 0.70710678118654752f));
            unsigned x = __float_as_uint(g); x += 0x7fffu + ((x >> 16) & 1u);
            At[quad * 4 + r][n] = (unsigned short)(x >> 16);
        }
        acc[nt] = (f32x4){0.f, 0.f, 0.f, 0.f};
    }
    __syncthreads();

    // GEMM2
    #pragma unroll 2
    for (int ks = 0; ks < 16; ++ks) {
        int kb = ks * 32 + quad * 8;
        short8 af = *(const short8*)&At[ncol][kb];
        #pragma unroll
        for (int nt = 0; nt < 4; ++nt) {
            short8 bfr = *(const short8*)(bp2 + nt * 8192 + ks * 512);
            acc[nt] = __builtin_amdgcn_mfma_f32_16x16x32_bf16(af, bfr, acc[nt], 0, 0, 0);
        }
    }

    #pragma unroll
    for (int nt = 0; nt < 4; ++nt) {
        int n = wave * 64 + nt * 16 + ncol;
        float bias = b2[n];
        #pragma unroll
        for (int r = 0; r < 4; ++r)
            Ct[quad * 4 + r][n] = acc[nt][r] + bias;
    }
    __syncthreads();

    // LayerNorm: 32 threads per row; write in tgtPf fragment layout
    const int row = tid >> 5, l32 = tid & 31;
    const float4* cr = (const float4*)&Ct[row][0];
    float s = 0.f, q = 0.f;
    #pragma unroll
    for (int j = 0; j < 4; ++j) {
        float4 v = cr[l32 + 32 * j];
        s += v.x + v.y + v.z + v.w;
        q += v.x * v.x + v.y * v.y + v.z * v.z + v.w * v.w;
    }
    #pragma unroll
    for (int off = 16; off > 0; off >>= 1) {
        s += __shfl_down(s, off, 32);
        q += __shfl_down(q, off, 32);
    }
    if (l32 == 0) {
        float mu = s * (1.0f / Hh);
        float var = q * (1.0f / Hh) - mu * mu;
        stats[row][0] = mu;
        stats[row][1] = rsqrtf(var + 1e-5f);
    }
    __syncthreads();
    {
        float mu = stats[row][0], rs = stats[row][1];
        int r = r0 + row;
        int bb = r >> 7, u = r & 127;
        float* obase = tgtPf + (size_t)bb * 65536 + u * 8;
        #pragma unroll
        for (int j = 0; j < 4; ++j) {
            int c4 = l32 + 32 * j;
            float4 v = cr[c4];
            float4 g4 = ((const float4*)ln_g)[c4];
            float4 b4 = ((const float4*)ln_b)[c4];
            float4 o;
            o.x = (v.x - mu) * rs * g4.x + b4.x;
            o.y = (v.y - mu) * rs * g4.y + b4.y;
            o.z = (v.z - mu) * rs * g4.z + b4.z;
            o.w = (v.w - mu) * rs * g4.w + b4.w;
            *(float4*)(obase + (c4 >> 1) * 1024 + (c4 & 1) * 4) = o;
        }
    }
}

// -------- Joint: out[b,t,u,v] = tanh(src[b,t,:]+tgtP[b,u,:]) @ Wl + bl
// Block = (t-pair, b, u-half): waves 0,1 -> t0 (u 0..31 / 32..63 of half),
// waves 2,3 -> t0+1.  A-operand loads from tgtPf fragment layout: lane-
// contiguous (4x512B segments/wave-inst).  B-frags packed (1KB contiguous).
__global__ __launch_bounds__(256) void joint_mfma(
    const float* __restrict__ src, const float* __restrict__ tgtPf,
    const unsigned short* __restrict__ Wpl, const float* __restrict__ bl,
    float* __restrict__ out)
{
    __shared__ float srcl[2 * Hh];

    const int t0 = blockIdx.x * 2, b = blockIdx.y, uh = blockIdx.z;
    const int tid = threadIdx.x;
    const int lane = tid & 63, wave = tid >> 6;
    const int ncol = lane & 15, quad = lane >> 4;

    // stage the two src rows (contiguous 4KB)
    const float4* s4 = (const float4*)(src + ((size_t)(b * Tt + t0)) * Hh);
    ((float4*)srcl)[tid] = s4[tid];

    float bln[3];
    #pragma unroll
    for (int nt = 0; nt < 3; ++nt) {
        int n = nt * 16 + ncol;
        bln[nt] = (n < Vv) ? bl[n] : 0.0f;
    }

    f32x4 acc[2][3];
    #pragma unroll
    for (int mi = 0; mi < 2; ++mi)
        #pragma unroll
        for (int nt = 0; nt < 3; ++nt)
            acc[mi][nt] = (f32x4){0.f, 0.f, 0.f, 0.f};

    __syncthreads();

    const int u0 = uh * 64 + (wave & 1) * 32 + ncol;      // frag rows u0, u0+16
    const float* pA = tgtPf + (size_t)b * 65536 + u0 * 8;
    const float* srow = srcl + (wave >> 1) * Hh;
    const unsigned short* bp = Wpl + lane * 8;

    #pragma unroll 2
    for (int ks = 0; ks < 16; ++ks) {
        const int off = (ks * 4 + quad) * 1024;
        float4 a0 = *(const float4*)(pA + off);
        float4 a1 = *(const float4*)(pA + off + 4);
        float4 c0 = *(const float4*)(pA + off + 128);
        float4 c1 = *(const float4*)(pA + off + 132);
        const float* sp = srow + ks * 32 + quad * 8;
        float4 sA = *(const float4*)(sp);
        float4 sB = *(const float4*)(sp + 4);

        union { uint4 u; short8 s; } f0, f1;
        f0.u.x = tanh2_pack((v2f){sA.x + a0.x, sA.y + a0.y});
        f0.u.y = tanh2_pack((v2f){sA.z + a0.z, sA.w + a0.w});
        f0.u.z = tanh2_pack((v2f){sB.x + a1.x, sB.y + a1.y});
        f0.u.w = tanh2_pack((v2f){sB.z + a1.z, sB.w + a1.w});
        f1.u.x = tanh2_pack((v2f){sA.x + c0.x, sA.y + c0.y});
        f1.u.y = tanh2_pack((v2f){sA.z + c0.z, sA.w + c0.w});
        f1.u.z = tanh2_pack((v2f){sB.x + c1.x, sB.y + c1.y});
        f1.u.w = tanh2_pack((v2f){sB.z + c1.z, sB.w + c1.w});

        #pragma unroll
        for (int nt = 0; nt < 3; ++nt) {
            short8 bfr = *(const short8*)(bp + (nt * 16 + ks) * 512);
            acc[0][nt] = __builtin_amdgcn_mfma_f32_16x16x32_bf16(f0.s, bfr, acc[0][nt], 0, 0, 0);
            acc[1][nt] = __builtin_amdgcn_mfma_f32_16x16x32_bf16(f1.s, bfr, acc[1][nt], 0, 0, 0);
        }
    }

    // epilogue: C layout col=lane&15, row=quad*4+reg  (validated rounds 2-3)
    const int t = t0 + (wave >> 1);
    const int ub = uh * 64 + (wave & 1) * 32;
    float* ob = out + ((size_t)(b * Tt + t)) * Uu * Vv;
    #pragma unroll
    for (int mi = 0; mi < 2; ++mi) {
        #pragma unroll
        for (int nt = 0; nt < 3; ++nt) {
            int n = nt * 16 + ncol;
            if (n < Vv) {
                #pragma unroll
                for (int r = 0; r < 4; ++r) {
                    int m = ub + mi * 16 + quad * 4 + r;
                    ob[m * Vv + n] = acc[mi][nt][r] + bln[nt];
                }
            }
        }
    }
}

// -------- lengths passthrough (harness reads whole out buffer as f32)
__global__ void len_kernel(const int* __restrict__ sl, const int* __restrict__ tl,
                           float* __restrict__ dst)
{
    const int i = threadIdx.x;
    if (i < Bb)            dst[i] = (float)sl[i];
    else if (i < 2 * Bb)   dst[i] = (float)tl[i - Bb];
}

extern "C" void kernel_launch(void* const* d_in, const int* in_sizes, int n_in,
                              void* d_out, int out_size, void* d_ws, size_t ws_size,
                              hipStream_t stream)
{
    const float* src  = (const float*)d_in[0];
    const int*   slen = (const int*)  d_in[1];
    const float* tgt  = (const float*)d_in[2];
    const int*   tlen = (const int*)  d_in[3];
    const float* W1   = (const float*)d_in[4];
    const float* b1   = (const float*)d_in[5];
    const float* W2   = (const float*)d_in[6];
    const float* b2   = (const float*)d_in[7];
    const float* ln_g = (const float*)d_in[8];
    const float* ln_b = (const float*)d_in[9];
    const float* Wl   = (const float*)d_in[10];
    const float* bl   = (const float*)d_in[11];

    float* out = (float*)d_out;
    // ws: tgtPf fp32 1MB | Wp1 bf16 512KB | Wp2 bf16 512KB | Wpl bf16 48KB
    float* tgtPf = (float*)d_ws;
    unsigned short* Wp1 = (unsigned short*)((char*)d_ws + 1048576);
    unsigned short* Wp2 = (unsigned short*)((char*)d_ws + 1048576 + 524288);
    unsigned short* Wpl = (unsigned short*)((char*)d_ws + 2097152);

    hipLaunchKernelGGL(prep_pack, dim3(136), dim3(256), 0, stream,
                       W1, W2, Wl, Wp1, Wp2, Wpl);
    hipLaunchKernelGGL(target_kernel, dim3(Bb * Uu / 16), dim3(512), 0, stream,
                       tgt, Wp1, b1, Wp2, b2, ln_g, ln_b, tgtPf);
    hipLaunchKernelGGL(joint_mfma, dim3(Tt / 2, Bb, 2), dim3(256), 0, stream,
                       src, tgtPf, Wpl, bl, out);
    hipLaunchKernelGGL(len_kernel, dim3(1), dim3(64), 0, stream,
                       slen, tlen, out + (size_t)Bb * Tt * Uu * Vv);
}

// Round 5
// 144.430 us; speedup vs baseline: 2.8356x; 1.0394x over previous
//
#include <hip/hip_runtime.h>
#include <math.h>

#define Bb 4
#define Tt 512
#define Uu 128
#define Hh 512
#define Vv 41

typedef __attribute__((ext_vector_type(8))) short short8;
typedef __attribute__((ext_vector_type(4))) float f32x4;
typedef __attribute__((ext_vector_type(2))) float v2f;

// RNE bf16 pack of two floats -> u32 [lo | hi<<16]
__device__ __forceinline__ unsigned pack_bf16_rne(float hi, float lo) {
    unsigned xh = __float_as_uint(hi); xh += 0x7fffu + ((xh >> 16) & 1u);
    unsigned xl = __float_as_uint(lo); xl += 0x7fffu + ((xl >> 16) & 1u);
    return __builtin_amdgcn_perm(xh, xl, 0x07060302);
}

__device__ __forceinline__ unsigned short bf16_rne(float v) {
    unsigned x = __float_as_uint(v);
    x += 0x7fffu + ((x >> 16) & 1u);
    return (unsigned short)(x >> 16);
}

// tanh approx: med3-clamp to [-3,3], odd minimax cubic in t=x^2 (max err ~0.024).
// Packed v2f math -> v_pk_fma_f32; x0 -> low bf16, x1 -> high bf16.
__device__ __forceinline__ unsigned tanh2_pack(float x0, float x1) {
    v2f xc;
    xc.x = __builtin_amdgcn_fmed3f(x0, -3.0f, 3.0f);
    xc.y = __builtin_amdgcn_fmed3f(x1, -3.0f, 3.0f);
    v2f t = xc * xc;
    v2f p = t * (v2f){-0.00140725f, -0.00140725f} + (v2f){0.0288922f, 0.0288922f};
    p = p * t + (v2f){-0.2177528f, -0.2177528f};
    p = p * t + (v2f){0.9707868f, 0.9707868f};
    v2f g = xc * p;
    return __builtin_amdgcn_perm(__float_as_uint(g.y), __float_as_uint(g.x), 0x07060302);
}

// -------- Prep: pack W1,W2 (512x512) and Wl (512x41 -> n-pad 48) into MFMA
// B-fragment order Wp[ntile][kstep][lane][8 bf16] (wave B-load = 1KB contig).
// Also writes the two length vectors (block 135).
__global__ __launch_bounds__(256) void prep_pack(
    const float* __restrict__ W1, const float* __restrict__ W2,
    const float* __restrict__ Wl,
    unsigned short* __restrict__ Wp1, unsigned short* __restrict__ Wp2,
    unsigned short* __restrict__ Wpl,
    const int* __restrict__ sl, const int* __restrict__ tl,
    float* __restrict__ lenDst)
{
    __shared__ float T[64][65];
    const int bid = blockIdx.x, tid = threadIdx.x;

    if (bid == 135 && tid < 2 * Bb) {
        lenDst[tid] = (tid < Bb) ? (float)sl[tid] : (float)tl[tid - Bb];
    }

    const float* Wsrc; unsigned short* Wdst; int k0, n0, isWl;
    if (bid < 64)       { Wsrc = W1; Wdst = Wp1; k0 = (bid >> 3) * 64; n0 = (bid & 7) * 64; isWl = 0; }
    else if (bid < 128) { Wsrc = W2; Wdst = Wp2; k0 = ((bid - 64) >> 3) * 64; n0 = ((bid - 64) & 7) * 64; isWl = 0; }
    else                { Wsrc = Wl; Wdst = Wpl; k0 = (bid - 128) * 64; n0 = 0; isWl = 1; }

    #pragma unroll
    for (int i = 0; i < 16; ++i) {
        int idx = i * 256 + tid;                 // 0..4095
        int kk = idx >> 6, nn = idx & 63;
        float v;
        if (isWl) v = (nn < Vv) ? Wl[(k0 + kk) * Vv + nn] : 0.0f;
        else      v = Wsrc[(size_t)(k0 + kk) * 512 + n0 + nn];
        T[kk][nn] = v;
    }
    __syncthreads();

    #pragma unroll
    for (int i = 0; i < 2; ++i) {
        int task = i * 256 + tid;                // 0..511
        int nn = task & 63, kg = task >> 6;
        if (isWl && nn >= 48) continue;
        int n = n0 + nn, k = k0 + kg * 8;
        float e[8];
        #pragma unroll
        for (int j = 0; j < 8; ++j) e[j] = T[kg * 8 + j][nn];
        uint4 pk;
        pk.x = pack_bf16_rne(e[1], e[0]);
        pk.y = pack_bf16_rne(e[3], e[2]);
        pk.z = pack_bf16_rne(e[5], e[4]);
        pk.w = pack_bf16_rne(e[7], e[6]);
        int ntg = n >> 4, ncol = n & 15;
        int ks = (k >> 5) & 15, quad = (k >> 3) & 3;
        int lane = quad * 16 + ncol;
        *(uint4*)(Wdst + (size_t)((ntg * 16 + ks) * 64 + lane) * 8) = pk;
    }
}

// -------- Target path, fused MFMA: LN(gelu(tgt@W1+b1)@W2+b2) -> tgtPf
// tgtPf layout: [b][k/8][u][8 floats]  (joint A-operand fragment order).
// 32 blocks x 16 rows, 1024 threads (16 waves), wave owns 32 n-cols; B-frag
// register double-buffer to hide L2 latency.
__global__ __launch_bounds__(1024) void target_kernel(
    const float* __restrict__ tgt,
    const unsigned short* __restrict__ Wp1, const float* __restrict__ b1,
    const unsigned short* __restrict__ Wp2, const float* __restrict__ b2,
    const float* __restrict__ ln_g, const float* __restrict__ ln_b,
    float* __restrict__ tgtPf)
{
    __shared__ unsigned short At[16][520];   // 1040B stride: 2-way max (free)
    __shared__ float Ct[16][516];

    const int tid = threadIdx.x;
    const int lane = tid & 63, wave = tid >> 6;       // wave 0..15
    const int ncol = lane & 15, quad = lane >> 4;
    const int r0 = blockIdx.x * 16;

    {   // stage A: 16 rows x 512 fp32 -> bf16 LDS
        const float4* t4 = (const float4*)(tgt + (size_t)r0 * Hh);
        #pragma unroll
        for (int j = 0; j < 2; ++j) {
            int fi = tid + j * 1024;
            int row = fi >> 7, c4 = fi & 127;
            float4 v = t4[fi];
            uint2 pk;
            pk.x = pack_bf16_rne(v.y, v.x);
            pk.y = pack_bf16_rne(v.w, v.z);
            *(uint2*)&At[row][c4 * 4] = pk;
        }
    }
    __syncthreads();

    f32x4 acc[2];
    acc[0] = (f32x4){0.f, 0.f, 0.f, 0.f};
    acc[1] = (f32x4){0.f, 0.f, 0.f, 0.f};

    const unsigned short* bp1 = Wp1 + (size_t)(wave * 2) * 8192 + lane * 8;
    const unsigned short* bp2 = Wp2 + (size_t)(wave * 2) * 8192 + lane * 8;

    {   // GEMM1, B double-buffered
        short8 cb0 = *(const short8*)(bp1);
        short8 cb1 = *(const short8*)(bp1 + 8192);
        #pragma unroll
        for (int ks = 0; ks < 16; ++ks) {
            short8 nb0, nb1;
            if (ks < 15) {
                nb0 = *(const short8*)(bp1 + (ks + 1) * 512);
                nb1 = *(const short8*)(bp1 + 8192 + (ks + 1) * 512);
            }
            short8 af = *(const short8*)&At[ncol][ks * 32 + quad * 8];
            acc[0] = __builtin_amdgcn_mfma_f32_16x16x32_bf16(af, cb0, acc[0], 0, 0, 0);
            acc[1] = __builtin_amdgcn_mfma_f32_16x16x32_bf16(af, cb1, acc[1], 0, 0, 0);
            cb0 = nb0; cb1 = nb1;
        }
    }
    __syncthreads();

    // GELU(+b1) -> At (reuse)
    #pragma unroll
    for (int nt = 0; nt < 2; ++nt) {
        int n = wave * 32 + nt * 16 + ncol;
        float bias = b1[n];
        #pragma unroll
        for (int r = 0; r < 4; ++r) {
            float v = acc[nt][r] + bias;
            float g = 0.5f * v * (1.0f + erff(v * 0.70710678118654752f));
            At[quad * 4 + r][n] = bf16_rne(g);
        }
        acc[nt] = (f32x4){0.f, 0.f, 0.f, 0.f};
    }
    __syncthreads();

    {   // GEMM2, B double-buffered
        short8 cb0 = *(const short8*)(bp2);
        short8 cb1 = *(const short8*)(bp2 + 8192);
        #pragma unroll
        for (int ks = 0; ks < 16; ++ks) {
            short8 nb0, nb1;
            if (ks < 15) {
                nb0 = *(const short8*)(bp2 + (ks + 1) * 512);
                nb1 = *(const short8*)(bp2 + 8192 + (ks + 1) * 512);
            }
            short8 af = *(const short8*)&At[ncol][ks * 32 + quad * 8];
            acc[0] = __builtin_amdgcn_mfma_f32_16x16x32_bf16(af, cb0, acc[0], 0, 0, 0);
            acc[1] = __builtin_amdgcn_mfma_f32_16x16x32_bf16(af, cb1, acc[1], 0, 0, 0);
            cb0 = nb0; cb1 = nb1;
        }
    }

    #pragma unroll
    for (int nt = 0; nt < 2; ++nt) {
        int n = wave * 32 + nt * 16 + ncol;
        float bias = b2[n];
        #pragma unroll
        for (int r = 0; r < 4; ++r)
            Ct[quad * 4 + r][n] = acc[nt][r] + bias;
    }
    __syncthreads();

    // LayerNorm: one wave per row, xor-shuffle reduce, float2 LDS reads (2-way free)
    {
        const int row = wave;
        const float2* cr2 = (const float2*)&Ct[row][0];
        float2 vv[4];
        float s = 0.f, q = 0.f;
        #pragma unroll
        for (int j = 0; j < 4; ++j) {
            float2 v = cr2[lane + 64 * j];
            vv[j] = v;
            s += v.x + v.y;
            q += v.x * v.x + v.y * v.y;
        }
        #pragma unroll
        for (int off = 32; off > 0; off >>= 1) {
            s += __shfl_xor(s, off, 64);
            q += __shfl_xor(q, off, 64);
        }
        float mu = s * (1.0f / Hh);
        float rs = rsqrtf(q * (1.0f / Hh) - mu * mu + 1e-5f);
        int r = r0 + row;
        int bb = r >> 7, u = r & 127;
        float* obase = tgtPf + (size_t)bb * 65536 + u * 8;
        #pragma unroll
        for (int j = 0; j < 4; ++j) {
            int k2 = lane + 64 * j;
            int k = k2 * 2;
            float2 g2 = ((const float2*)ln_g)[k2];
            float2 bv = ((const float2*)ln_b)[k2];
            float2 o;
            o.x = (vv[j].x - mu) * rs * g2.x + bv.x;
            o.y = (vv[j].y - mu) * rs * g2.y + bv.y;
            *(float2*)(obase + ((k >> 3) << 10) + (k & 7)) = o;
        }
    }
}

// -------- Joint: out[b,t,u,v] = tanh(src[b,t,:]+tgtP[b,u,:]) @ Wl + bl
// Block = (t-pair, b, u-half).  Software-pipelined: A-frags for kstep+1
// prefetched from global while tanh/MFMA of kstep runs.
__global__ __launch_bounds__(256) void joint_mfma(
    const float* __restrict__ src, const float* __restrict__ tgtPf,
    const unsigned short* __restrict__ Wpl, const float* __restrict__ bl,
    float* __restrict__ out)
{
    __shared__ float srcl[2 * Hh];

    const int t0 = blockIdx.x * 2, b = blockIdx.y, uh = blockIdx.z;
    const int tid = threadIdx.x;
    const int lane = tid & 63, wave = tid >> 6;
    const int ncol = lane & 15, quad = lane >> 4;

    // stage the two src rows (contiguous 4KB)
    const float4* s4 = (const float4*)(src + ((size_t)(b * Tt + t0)) * Hh);
    ((float4*)srcl)[tid] = s4[tid];

    const int u0 = uh * 64 + (wave & 1) * 32 + ncol;      // frag rows u0, u0+16
    const float* pA = tgtPf + (size_t)b * 65536 + u0 * 8;
    const unsigned short* bp = Wpl + lane * 8;

    // prefetch kstep 0 A-frags (global, independent of LDS barrier)
    float4 a0 = *(const float4*)(pA + quad * 1024);
    float4 a1 = *(const float4*)(pA + quad * 1024 + 4);
    float4 c0 = *(const float4*)(pA + quad * 1024 + 128);
    float4 c1 = *(const float4*)(pA + quad * 1024 + 132);

    float bln[3];
    #pragma unroll
    for (int nt = 0; nt < 3; ++nt) {
        int n = nt * 16 + ncol;
        bln[nt] = (n < Vv) ? bl[n] : 0.0f;
    }

    f32x4 acc[2][3];
    #pragma unroll
    for (int mi = 0; mi < 2; ++mi)
        #pragma unroll
        for (int nt = 0; nt < 3; ++nt)
            acc[mi][nt] = (f32x4){0.f, 0.f, 0.f, 0.f};

    __syncthreads();

    const float* srow = srcl + (wave >> 1) * Hh;

    #pragma unroll 4
    for (int ks = 0; ks < 16; ++ks) {
        float4 na0, na1, nc0, nc1;
        if (ks < 15) {
            const float* pn = pA + ((ks + 1) * 4 + quad) * 1024;
            na0 = *(const float4*)(pn);
            na1 = *(const float4*)(pn + 4);
            nc0 = *(const float4*)(pn + 128);
            nc1 = *(const float4*)(pn + 132);
        }
        const float* sp = srow + ks * 32 + quad * 8;
        float4 sA = *(const float4*)(sp);
        float4 sB = *(const float4*)(sp + 4);

        union { uint4 u; short8 s; } f0, f1;
        f0.u.x = tanh2_pack(sA.x + a0.x, sA.y + a0.y);
        f0.u.y = tanh2_pack(sA.z + a0.z, sA.w + a0.w);
        f0.u.z = tanh2_pack(sB.x + a1.x, sB.y + a1.y);
        f0.u.w = tanh2_pack(sB.z + a1.z, sB.w + a1.w);
        f1.u.x = tanh2_pack(sA.x + c0.x, sA.y + c0.y);
        f1.u.y = tanh2_pack(sA.z + c0.z, sA.w + c0.w);
        f1.u.z = tanh2_pack(sB.x + c1.x, sB.y + c1.y);
        f1.u.w = tanh2_pack(sB.z + c1.z, sB.w + c1.w);

        #pragma unroll
        for (int nt = 0; nt < 3; ++nt) {
            short8 bfr = *(const short8*)(bp + (nt * 16 + ks) * 512);
            acc[0][nt] = __builtin_amdgcn_mfma_f32_16x16x32_bf16(f0.s, bfr, acc[0][nt], 0, 0, 0);
            acc[1][nt] = __builtin_amdgcn_mfma_f32_16x16x32_bf16(f1.s, bfr, acc[1][nt], 0, 0, 0);
        }
        a0 = na0; a1 = na1; c0 = nc0; c1 = nc1;
    }

    // epilogue: C layout col=lane&15, row=quad*4+reg  (validated rounds 2-4)
    const int t = t0 + (wave >> 1);
    const int ub = uh * 64 + (wave & 1) * 32;
    float* ob = out + ((size_t)(b * Tt + t)) * Uu * Vv;
    #pragma unroll
    for (int mi = 0; mi < 2; ++mi) {
        #pragma unroll
        for (int nt = 0; nt < 3; ++nt) {
            int n = nt * 16 + ncol;
            if (n < Vv) {
                #pragma unroll
                for (int r = 0; r < 4; ++r) {
                    int m = ub + mi * 16 + quad * 4 + r;
                    ob[m * Vv + n] = acc[mi][nt][r] + bln[nt];
                }
            }
        }
    }
}

extern "C" void kernel_launch(void* const* d_in, const int* in_sizes, int n_in,
                              void* d_out, int out_size, void* d_ws, size_t ws_size,
                              hipStream_t stream)
{
    const float* src  = (const float*)d_in[0];
    const int*   slen = (const int*)  d_in[1];
    const float* tgt  = (const float*)d_in[2];
    const int*   tlen = (const int*)  d_in[3];
    const float* W1   = (const float*)d_in[4];
    const float* b1   = (const float*)d_in[5];
    const float* W2   = (const float*)d_in[6];
    const float* b2   = (const float*)d_in[7];
    const float* ln_g = (const float*)d_in[8];
    const float* ln_b = (const float*)d_in[9];
    const float* Wl   = (const float*)d_in[10];
    const float* bl   = (const float*)d_in[11];

    float* out = (float*)d_out;
    // ws: tgtPf fp32 1MB | Wp1 bf16 512KB | Wp2 bf16 512KB | Wpl bf16 48KB
    float* tgtPf = (float*)d_ws;
    unsigned short* Wp1 = (unsigned short*)((char*)d_ws + 1048576);
    unsigned short* Wp2 = (unsigned short*)((char*)d_ws + 1048576 + 524288);
    unsigned short* Wpl = (unsigned short*)((char*)d_ws + 2097152);

    hipLaunchKernelGGL(prep_pack, dim3(136), dim3(256), 0, stream,
                       W1, W2, Wl, Wp1, Wp2, Wpl,
                       slen, tlen, out + (size_t)Bb * Tt * Uu * Vv);
    hipLaunchKernelGGL(target_kernel, dim3(Bb * Uu / 16), dim3(1024), 0, stream,
                       tgt, Wp1, b1, Wp2, b2, ln_g, ln_b, tgtPf);
    hipLaunchKernelGGL(joint_mfma, dim3(Tt / 2, Bb, 2), dim3(256), 0, stream,
                       src, tgtPf, Wpl, bl, out);
}

// Round 6
// 141.549 us; speedup vs baseline: 2.8933x; 1.0203x over previous
//
#include <hip/hip_runtime.h>
#include <math.h>

#define Bb 4
#define Tt 512
#define Uu 128
#define Hh 512
#define Vv 41

typedef __attribute__((ext_vector_type(8))) short short8;
typedef __attribute__((ext_vector_type(4))) float f32x4;
typedef __attribute__((ext_vector_type(2))) float v2f;

// RNE bf16 pack of two floats -> u32 [lo | hi<<16]
__device__ __forceinline__ unsigned pack_bf16_rne(float hi, float lo) {
    unsigned xh = __float_as_uint(hi); xh += 0x7fffu + ((xh >> 16) & 1u);
    unsigned xl = __float_as_uint(lo); xl += 0x7fffu + ((xl >> 16) & 1u);
    return __builtin_amdgcn_perm(xh, xl, 0x07060302);
}

__device__ __forceinline__ unsigned short bf16_rne(float v) {
    unsigned x = __float_as_uint(v);
    x += 0x7fffu + ((x >> 16) & 1u);
    return (unsigned short)(x >> 16);
}

// tanh approx: med3-clamp to [-3,3], odd minimax cubic in t=x^2 (max err ~0.024).
__device__ __forceinline__ unsigned tanh2_pack(float x0, float x1) {
    v2f xc;
    xc.x = __builtin_amdgcn_fmed3f(x0, -3.0f, 3.0f);
    xc.y = __builtin_amdgcn_fmed3f(x1, -3.0f, 3.0f);
    v2f t = xc * xc;
    v2f p = t * (v2f){-0.00140725f, -0.00140725f} + (v2f){0.0288922f, 0.0288922f};
    p = p * t + (v2f){-0.2177528f, -0.2177528f};
    p = p * t + (v2f){0.9707868f, 0.9707868f};
    v2f g = xc * p;
    return __builtin_amdgcn_perm(__float_as_uint(g.y), __float_as_uint(g.x), 0x07060302);
}

// -------- Prep: blocks 0..135: pack W1,W2,Wl into MFMA B-frag order
// Wp[ntile][kstep][lane][8 bf16]; block 135 also writes lengths.
// Blocks 136..167: pack tgt (512x512 fp32) into A-frag order
// tgtA[rowtile 32][kstep 16][lane 64][8 bf16].
__global__ __launch_bounds__(256) void prep_pack(
    const float* __restrict__ W1, const float* __restrict__ W2,
    const float* __restrict__ Wl, const float* __restrict__ tgt,
    unsigned short* __restrict__ Wp1, unsigned short* __restrict__ Wp2,
    unsigned short* __restrict__ Wpl, unsigned short* __restrict__ tgtA,
    const int* __restrict__ sl, const int* __restrict__ tl,
    float* __restrict__ lenDst)
{
    __shared__ __align__(16) char smem[16640];
    const int bid = blockIdx.x, tid = threadIdx.x;

    if (bid >= 136) {   // ---- tgt -> A-frag pack
        unsigned short (*At)[520] = (unsigned short (*)[520])smem;
        const int rt = bid - 136;
        const float4* t4 = (const float4*)(tgt + (size_t)rt * 16 * Hh);
        #pragma unroll
        for (int j = 0; j < 8; ++j) {
            int fi = j * 256 + tid;            // 0..2047
            int row = fi >> 7, c4 = fi & 127;
            float4 v = t4[fi];
            uint2 pk;
            pk.x = pack_bf16_rne(v.y, v.x);
            pk.y = pack_bf16_rne(v.w, v.z);
            *(uint2*)&At[row][c4 * 4] = pk;
        }
        __syncthreads();
        #pragma unroll
        for (int i = 0; i < 4; ++i) {
            int chunk = i * 256 + tid;         // 0..1023
            int ks = chunk >> 6, l = chunk & 63;
            int q = l >> 4, nc = l & 15;
            short8 v = *(const short8*)&At[nc][ks * 32 + q * 8];
            *(short8*)(tgtA + ((size_t)(rt * 16 + ks) * 64 + l) * 8) = v;
        }
        return;
    }

    if (bid == 135 && tid < 2 * Bb)
        lenDst[tid] = (tid < Bb) ? (float)sl[tid] : (float)tl[tid - Bb];

    float (*T)[65] = (float (*)[65])smem;
    const float* Wsrc; unsigned short* Wdst; int k0, n0, isWl;
    if (bid < 64)       { Wsrc = W1; Wdst = Wp1; k0 = (bid >> 3) * 64; n0 = (bid & 7) * 64; isWl = 0; }
    else if (bid < 128) { Wsrc = W2; Wdst = Wp2; k0 = ((bid - 64) >> 3) * 64; n0 = ((bid - 64) & 7) * 64; isWl = 0; }
    else                { Wsrc = Wl; Wdst = Wpl; k0 = (bid - 128) * 64; n0 = 0; isWl = 1; }

    #pragma unroll
    for (int i = 0; i < 16; ++i) {
        int idx = i * 256 + tid;
        int kk = idx >> 6, nn = idx & 63;
        float v;
        if (isWl) v = (nn < Vv) ? Wl[(k0 + kk) * Vv + nn] : 0.0f;
        else      v = Wsrc[(size_t)(k0 + kk) * 512 + n0 + nn];
        T[kk][nn] = v;
    }
    __syncthreads();

    #pragma unroll
    for (int i = 0; i < 2; ++i) {
        int task = i * 256 + tid;
        int nn = task & 63, kg = task >> 6;
        if (isWl && nn >= 48) continue;
        int n = n0 + nn, k = k0 + kg * 8;
        float e[8];
        #pragma unroll
        for (int j = 0; j < 8; ++j) e[j] = T[kg * 8 + j][nn];
        uint4 pk;
        pk.x = pack_bf16_rne(e[1], e[0]);
        pk.y = pack_bf16_rne(e[3], e[2]);
        pk.z = pack_bf16_rne(e[5], e[4]);
        pk.w = pack_bf16_rne(e[7], e[6]);
        int ntg = n >> 4, ncol = n & 15;
        int ks = (k >> 5) & 15, quad = (k >> 3) & 3;
        int lane = quad * 16 + ncol;
        *(uint4*)(Wdst + (size_t)((ntg * 16 + ks) * 64 + lane) * 8) = pk;
    }
}

// -------- T1: h1 = gelu(tgt@W1 + b1), A/B from packed frags, out in A-frag
// order h1A[rowtile][kstep][lane][8].  Grid (8 nblk, 32 rowtile) x 128 thr.
__global__ __launch_bounds__(128) void gemm_t1(
    const unsigned short* __restrict__ tgtA,
    const unsigned short* __restrict__ Wp1, const float* __restrict__ b1,
    unsigned short* __restrict__ h1A)
{
    __shared__ unsigned short At[16][72];
    const int nb = blockIdx.x, rt = blockIdx.y;
    const int tid = threadIdx.x, lane = tid & 63, w = tid >> 6;
    const int ncol = lane & 15, quad = lane >> 4;
    const int nt0 = nb * 4 + w * 2;

    const unsigned short* ap = tgtA + ((size_t)rt * 1024 + lane) * 8;
    const unsigned short* bp = Wp1 + (size_t)lane * 8;

    f32x4 acc0 = (f32x4){0.f,0.f,0.f,0.f}, acc1 = (f32x4){0.f,0.f,0.f,0.f};
    short8 ac  = *(const short8*)(ap);
    short8 b0c = *(const short8*)(bp + (size_t)nt0 * 8192);
    short8 b1c = *(const short8*)(bp + (size_t)(nt0 + 1) * 8192);

    #pragma unroll
    for (int ks = 0; ks < 16; ++ks) {
        short8 an, b0n, b1n;
        if (ks < 15) {
            an  = *(const short8*)(ap + (ks + 1) * 512);
            b0n = *(const short8*)(bp + (size_t)nt0 * 8192 + (ks + 1) * 512);
            b1n = *(const short8*)(bp + (size_t)(nt0 + 1) * 8192 + (ks + 1) * 512);
        }
        acc0 = __builtin_amdgcn_mfma_f32_16x16x32_bf16(ac, b0c, acc0, 0, 0, 0);
        acc1 = __builtin_amdgcn_mfma_f32_16x16x32_bf16(ac, b1c, acc1, 0, 0, 0);
        ac = an; b0c = b0n; b1c = b1n;
    }

    #pragma unroll
    for (int nt = 0; nt < 2; ++nt) {
        int n = nb * 64 + w * 32 + nt * 16 + ncol;
        float bias = b1[n];
        f32x4 A = nt ? acc1 : acc0;
        #pragma unroll
        for (int r = 0; r < 4; ++r) {
            float v = A[r] + bias;
            float g = 0.5f * v * (1.0f + erff(v * 0.70710678118654752f));
            At[quad * 4 + r][w * 32 + nt * 16 + ncol] = bf16_rne(g);
        }
    }
    __syncthreads();

    // read back in A-frag order, coalesced global store
    {
        int g2 = w, l = lane;
        short8 v = *(const short8*)&At[l & 15][g2 * 32 + (l >> 4) * 8];
        int ksg = nb * 2 + g2;
        *(short8*)(h1A + ((size_t)(rt * 16 + ksg) * 64 + l) * 8) = v;
    }
}

// -------- T2: h2 = h1@W2 + b2 (fp32, row-major).  No barriers.
__global__ __launch_bounds__(128) void gemm_t2(
    const unsigned short* __restrict__ h1A,
    const unsigned short* __restrict__ Wp2, const float* __restrict__ b2,
    float* __restrict__ h2)
{
    const int nb = blockIdx.x, rt = blockIdx.y;
    const int tid = threadIdx.x, lane = tid & 63, w = tid >> 6;
    const int ncol = lane & 15, quad = lane >> 4;
    const int nt0 = nb * 4 + w * 2;

    const unsigned short* ap = h1A + ((size_t)rt * 1024 + lane) * 8;
    const unsigned short* bp = Wp2 + (size_t)lane * 8;

    f32x4 acc0 = (f32x4){0.f,0.f,0.f,0.f}, acc1 = (f32x4){0.f,0.f,0.f,0.f};
    short8 ac  = *(const short8*)(ap);
    short8 b0c = *(const short8*)(bp + (size_t)nt0 * 8192);
    short8 b1c = *(const short8*)(bp + (size_t)(nt0 + 1) * 8192);

    #pragma unroll
    for (int ks = 0; ks < 16; ++ks) {
        short8 an, b0n, b1n;
        if (ks < 15) {
            an  = *(const short8*)(ap + (ks + 1) * 512);
            b0n = *(const short8*)(bp + (size_t)nt0 * 8192 + (ks + 1) * 512);
            b1n = *(const short8*)(bp + (size_t)(nt0 + 1) * 8192 + (ks + 1) * 512);
        }
        acc0 = __builtin_amdgcn_mfma_f32_16x16x32_bf16(ac, b0c, acc0, 0, 0, 0);
        acc1 = __builtin_amdgcn_mfma_f32_16x16x32_bf16(ac, b1c, acc1, 0, 0, 0);
        ac = an; b0c = b0n; b1c = b1n;
    }

    #pragma unroll
    for (int nt = 0; nt < 2; ++nt) {
        int n = nb * 64 + w * 32 + nt * 16 + ncol;
        float bias = b2[n];
        f32x4 A = nt ? acc1 : acc0;
        #pragma unroll
        for (int r = 0; r < 4; ++r)
            h2[(size_t)(rt * 16 + quad * 4 + r) * 512 + n] = A[r] + bias;
    }
}

// -------- T3: LayerNorm per row -> tgtPf [b][k/8][u][8] (joint A layout).
// One wave per row; 128 blocks x 256 thr.
__global__ __launch_bounds__(256) void ln_kernel(
    const float* __restrict__ h2, const float* __restrict__ ln_g,
    const float* __restrict__ ln_b, float* __restrict__ tgtPf)
{
    const int r = blockIdx.x * 4 + (threadIdx.x >> 6);
    const int lane = threadIdx.x & 63;
    const float4* row4 = (const float4*)(h2 + (size_t)r * Hh);
    float4 v0 = row4[lane], v1 = row4[lane + 64];
    float s = v0.x + v0.y + v0.z + v0.w + v1.x + v1.y + v1.z + v1.w;
    float q = v0.x*v0.x + v0.y*v0.y + v0.z*v0.z + v0.w*v0.w
            + v1.x*v1.x + v1.y*v1.y + v1.z*v1.z + v1.w*v1.w;
    #pragma unroll
    for (int off = 32; off > 0; off >>= 1) {
        s += __shfl_xor(s, off, 64);
        q += __shfl_xor(q, off, 64);
    }
    float mu = s * (1.0f / Hh);
    float rs = rsqrtf(q * (1.0f / Hh) - mu * mu + 1e-5f);

    float4 g0 = ((const float4*)ln_g)[lane], g1 = ((const float4*)ln_g)[lane + 64];
    float4 be0 = ((const float4*)ln_b)[lane], be1 = ((const float4*)ln_b)[lane + 64];
    float4 o0, o1;
    o0.x = (v0.x - mu) * rs * g0.x + be0.x;  o0.y = (v0.y - mu) * rs * g0.y + be0.y;
    o0.z = (v0.z - mu) * rs * g0.z + be0.z;  o0.w = (v0.w - mu) * rs * g0.w + be0.w;
    o1.x = (v1.x - mu) * rs * g1.x + be1.x;  o1.y = (v1.y - mu) * rs * g1.y + be1.y;
    o1.z = (v1.z - mu) * rs * g1.z + be1.z;  o1.w = (v1.w - mu) * rs * g1.w + be1.w;

    const int bb = r >> 7, u = r & 127;
    float* ob = tgtPf + (size_t)bb * 65536 + u * 8;
    int k0 = lane * 4;
    *(float4*)(ob + (k0 >> 3) * 1024 + (k0 & 7)) = o0;
    int k1 = lane * 4 + 256;
    *(float4*)(ob + (k1 >> 3) * 1024 + (k1 & 7)) = o1;
}

// -------- Joint: out[b,t,u,v] = tanh(src[b,t,:]+tgtP[b,u,:]) @ Wl + bl
// Fully software-pipelined: A-frags (global), B-frags (global), and src
// (LDS) all double-buffered one kstep ahead; bias folded into acc init.
__global__ __launch_bounds__(256) void joint_mfma(
    const float* __restrict__ src, const float* __restrict__ tgtPf,
    const unsigned short* __restrict__ Wpl, const float* __restrict__ bl,
    float* __restrict__ out)
{
    __shared__ float srcl[2 * Hh];

    const int t0 = blockIdx.x * 2, b = blockIdx.y, uh = blockIdx.z;
    const int tid = threadIdx.x;
    const int lane = tid & 63, wave = tid >> 6;
    const int ncol = lane & 15, quad = lane >> 4;

    const float4* s4 = (const float4*)(src + ((size_t)(b * Tt + t0)) * Hh);
    ((float4*)srcl)[tid] = s4[tid];

    const int u0 = uh * 64 + (wave & 1) * 32 + ncol;
    const float* pA = tgtPf + (size_t)b * 65536 + u0 * 8;
    const unsigned short* bp = Wpl + (size_t)lane * 8;

    // ks=0 global prefetch
    float4 a0 = *(const float4*)(pA + quad * 1024);
    float4 a1 = *(const float4*)(pA + quad * 1024 + 4);
    float4 c0 = *(const float4*)(pA + quad * 1024 + 128);
    float4 c1 = *(const float4*)(pA + quad * 1024 + 132);
    short8 B0 = *(const short8*)(bp);
    short8 B1 = *(const short8*)(bp + 8192);
    short8 B2 = *(const short8*)(bp + 16384);

    f32x4 acc[2][3];
    #pragma unroll
    for (int nt = 0; nt < 3; ++nt) {
        int n = nt * 16 + ncol;
        float bv = (n < Vv) ? bl[n] : 0.0f;
        acc[0][nt] = (f32x4){bv, bv, bv, bv};
        acc[1][nt] = (f32x4){bv, bv, bv, bv};
    }

    __syncthreads();
    const float* srow = srcl + (wave >> 1) * Hh;
    float4 sA = *(const float4*)(srow + quad * 8);
    float4 sB = *(const float4*)(srow + quad * 8 + 4);

    #pragma unroll 4
    for (int ks = 0; ks < 16; ++ks) {
        float4 na0, na1, nc0, nc1, nsA, nsB;
        short8 nB0, nB1, nB2;
        if (ks < 15) {
            const float* pn = pA + ((ks + 1) * 4 + quad) * 1024;
            na0 = *(const float4*)(pn);
            na1 = *(const float4*)(pn + 4);
            nc0 = *(const float4*)(pn + 128);
            nc1 = *(const float4*)(pn + 132);
            nB0 = *(const short8*)(bp + (ks + 1) * 512);
            nB1 = *(const short8*)(bp + 8192 + (ks + 1) * 512);
            nB2 = *(const short8*)(bp + 16384 + (ks + 1) * 512);
            const float* spn = srow + (ks + 1) * 32 + quad * 8;
            nsA = *(const float4*)(spn);
            nsB = *(const float4*)(spn + 4);
        }

        union { uint4 u; short8 s; } f0, f1;
        f0.u.x = tanh2_pack(sA.x + a0.x, sA.y + a0.y);
        f0.u.y = tanh2_pack(sA.z + a0.z, sA.w + a0.w);
        f0.u.z = tanh2_pack(sB.x + a1.x, sB.y + a1.y);
        f0.u.w = tanh2_pack(sB.z + a1.z, sB.w + a1.w);
        f1.u.x = tanh2_pack(sA.x + c0.x, sA.y + c0.y);
        f1.u.y = tanh2_pack(sA.z + c0.z, sA.w + c0.w);
        f1.u.z = tanh2_pack(sB.x + c1.x, sB.y + c1.y);
        f1.u.w = tanh2_pack(sB.z + c1.z, sB.w + c1.w);

        acc[0][0] = __builtin_amdgcn_mfma_f32_16x16x32_bf16(f0.s, B0, acc[0][0], 0, 0, 0);
        acc[1][0] = __builtin_amdgcn_mfma_f32_16x16x32_bf16(f1.s, B0, acc[1][0], 0, 0, 0);
        acc[0][1] = __builtin_amdgcn_mfma_f32_16x16x32_bf16(f0.s, B1, acc[0][1], 0, 0, 0);
        acc[1][1] = __builtin_amdgcn_mfma_f32_16x16x32_bf16(f1.s, B1, acc[1][1], 0, 0, 0);
        acc[0][2] = __builtin_amdgcn_mfma_f32_16x16x32_bf16(f0.s, B2, acc[0][2], 0, 0, 0);
        acc[1][2] = __builtin_amdgcn_mfma_f32_16x16x32_bf16(f1.s, B2, acc[1][2], 0, 0, 0);

        a0 = na0; a1 = na1; c0 = nc0; c1 = nc1;
        B0 = nB0; B1 = nB1; B2 = nB2;
        sA = nsA; sB = nsB;
    }

    // epilogue: C layout col=lane&15, row=quad*4+reg (validated r2-r5)
    const int t = t0 + (wave >> 1);
    const int ub = uh * 64 + (wave & 1) * 32;
    float* ob = out + ((size_t)(b * Tt + t)) * Uu * Vv;
    #pragma unroll
    for (int mi = 0; mi < 2; ++mi) {
        #pragma unroll
        for (int nt = 0; nt < 3; ++nt) {
            int n = nt * 16 + ncol;
            if (n < Vv) {
                #pragma unroll
                for (int r = 0; r < 4; ++r) {
                    int m = ub + mi * 16 + quad * 4 + r;
                    ob[m * Vv + n] = acc[mi][nt][r];
                }
            }
        }
    }
}

extern "C" void kernel_launch(void* const* d_in, const int* in_sizes, int n_in,
                              void* d_out, int out_size, void* d_ws, size_t ws_size,
                              hipStream_t stream)
{
    const float* src  = (const float*)d_in[0];
    const int*   slen = (const int*)  d_in[1];
    const float* tgt  = (const float*)d_in[2];
    const int*   tlen = (const int*)  d_in[3];
    const float* W1   = (const float*)d_in[4];
    const float* b1   = (const float*)d_in[5];
    const float* W2   = (const float*)d_in[6];
    const float* b2   = (const float*)d_in[7];
    const float* ln_g = (const float*)d_in[8];
    const float* ln_b = (const float*)d_in[9];
    const float* Wl   = (const float*)d_in[10];
    const float* bl   = (const float*)d_in[11];

    float* out = (float*)d_out;
    char* ws = (char*)d_ws;
    // ws: tgtPf 1MB | Wp1 512K | Wp2 512K | Wpl 64K | tgtA 512K | h1A 512K | h2 1MB
    float*          tgtPf = (float*)(ws);
    unsigned short* Wp1   = (unsigned short*)(ws + 1048576);
    unsigned short* Wp2   = (unsigned short*)(ws + 1572864);
    unsigned short* Wpl   = (unsigned short*)(ws + 2097152);
    unsigned short* tgtA  = (unsigned short*)(ws + 2162688);
    unsigned short* h1A   = (unsigned short*)(ws + 2686976);
    float*          h2    = (float*)(ws + 3211264);

    hipLaunchKernelGGL(prep_pack, dim3(168), dim3(256), 0, stream,
                       W1, W2, Wl, tgt, Wp1, Wp2, Wpl, tgtA,
                       slen, tlen, out + (size_t)Bb * Tt * Uu * Vv);
    hipLaunchKernelGGL(gemm_t1, dim3(8, 32), dim3(128), 0, stream,
                       tgtA, Wp1, b1, h1A);
    hipLaunchKernelGGL(gemm_t2, dim3(8, 32), dim3(128), 0, stream,
                       h1A, Wp2, b2, h2);
    hipLaunchKernelGGL(ln_kernel, dim3(128), dim3(256), 0, stream,
                       h2, ln_g, ln_b, tgtPf);
    hipLaunchKernelGGL(joint_mfma, dim3(Tt / 2, Bb, 2), dim3(256), 0, stream,
                       src, tgtPf, Wpl, bl, out);
}